// Round 7
// baseline (69.157 us; speedup 1.0000x reference)
//
#include <hip/hip_runtime.h>
#include <hip/hip_bf16.h>

typedef __attribute__((ext_vector_type(4))) float f32x4;
typedef __attribute__((ext_vector_type(8))) short bf16x8;

constexpr int B = 4, C = 64, N = 4096;
constexpr int KVSPLIT = 8;
constexpr int CHUNK = N / KVSPLIT;   // 512

__device__ __forceinline__ float bf2f(ushort u) {
    union { float f; unsigned int u32; } x;
    x.u32 = ((unsigned int)u) << 16;
    return x.f;
}
__device__ __forceinline__ ushort f2bf(float f) {
    union { float f; unsigned int u; } x;
    x.f = f;
    unsigned int r = x.u + 0x7FFFu + ((x.u >> 16) & 1u);
    return (ushort)(r >> 16);
}
// guaranteed-order pair: lo 16 = a (even index), hi 16 = b (odd index)
__device__ __forceinline__ uint packbf2(float a, float b) {
    return (uint)f2bf(a) | ((uint)f2bf(b) << 16);
}
__device__ __forceinline__ bf16x8 pack8(uint a, uint b, uint c, uint d) {
    union { uint u[4]; bf16x8 v; } x;
    x.u[0] = a; x.u[1] = b; x.u[2] = c; x.u[3] = d;
    return x.v;
}

#define MFMA16(a, b, c) __builtin_amdgcn_mfma_f32_16x16x32_bf16(a, b, c, 0, 0, 0)

// ---------------------------------------------------------------------------
// Kernel 1: QKV via MFMA (R6-passed), zero LDS/barriers + zero-init of HT/l
// (exactly 4 HT floats per thread; kernel-boundary orders it before attn).
// ---------------------------------------------------------------------------
__global__ __launch_bounds__(256) void qkv_kernel(
    const float* __restrict__ x, const float* __restrict__ Wq,
    const float* __restrict__ Wk, const float* __restrict__ Wv,
    ushort* __restrict__ Q, ushort* __restrict__ K, ushort* __restrict__ Vt,
    float* __restrict__ HT, float* __restrict__ l)
{
    const int b  = blockIdx.x >> 8;
    const int n0 = (blockIdx.x & 255) << 4;
    const int lane = threadIdx.x & 63;
    const int w  = threadIdx.x >> 6;
    const int lq = lane & 15, lg = lane >> 4;

    {   // zero accumulators for this launch (deterministic across replays)
        const int g = blockIdx.x * 256 + threadIdx.x;     // 0..262143
        const float4 z = {0.f, 0.f, 0.f, 0.f};
        *(float4*)(HT + (size_t)g * 4) = z;               // 4*262144 = B*N*C
        if (g < B * N) l[g] = 0.f;
    }

    bf16x8 bfrag[2];
#pragma unroll
    for (int kk = 0; kk < 2; ++kk) {
        float xv[8];
#pragma unroll
        for (int j = 0; j < 8; ++j)
            xv[j] = x[(size_t)(b * C + kk * 32 + lg * 8 + j) * N + n0 + lq];
        bfrag[kk] = pack8(packbf2(xv[0], xv[1]), packbf2(xv[2], xv[3]),
                          packbf2(xv[4], xv[5]), packbf2(xv[6], xv[7]));
    }

    const float* Ws[3] = {Wq, Wk, Wv};
#pragma unroll
    for (int m = 0; m < 3; ++m) {
        const float scale = (m == 0) ? 0.125f : 1.0f;
        f32x4 acc = {0.f, 0.f, 0.f, 0.f};
#pragma unroll
        for (int kk = 0; kk < 2; ++kk) {
            const float* wp = Ws[m] + (size_t)(w * 16 + lq) * C + kk * 32 + lg * 8;
            const float4 w0 = *(const float4*)wp;
            const float4 w1 = *(const float4*)(wp + 4);
            const bf16x8 af = pack8(
                packbf2(w0.x * scale, w0.y * scale), packbf2(w0.z * scale, w0.w * scale),
                packbf2(w1.x * scale, w1.y * scale), packbf2(w1.z * scale, w1.w * scale));
            acc = MFMA16(af, bfrag[kk], acc);
        }
        if (m < 2) {   // Q/K [b][n][c]
            uint2 u;
            u.x = packbf2(acc[0], acc[1]);
            u.y = packbf2(acc[2], acc[3]);
            ushort* dst = (m == 0 ? Q : K) + ((size_t)(b * N + n0 + lq)) * C + w * 16 + 4 * lg;
            *(uint2*)dst = u;
        } else {       // Vt [b][c][n]
#pragma unroll
            for (int j = 0; j < 4; ++j)
                Vt[(size_t)(b * C + w * 16 + 4 * lg + j) * N + n0 + lq] = f2bf(acc[j]);
        }
    }
}

// ---------------------------------------------------------------------------
// Kernel 2: split-KV attention (R5/R6-passed inner loop, UNCHANGED).
// Changes: KVSPLIT 4->8 (2048 blocks, ~7 blocks/CU resident; s=blk&7 puts one
// KV chunk per XCD L2), epilogue -> fp32 atomicAdd into HT/l (no pacc).
// ---------------------------------------------------------------------------
__global__ __launch_bounds__(256, 7) void attn_kernel(
    const ushort* __restrict__ Q, const ushort* __restrict__ K,
    const ushort* __restrict__ Vt, float* __restrict__ HT,
    float* __restrict__ l)
{
    __shared__ ushort Ks[2][32][68];                              // 136B rows
    __shared__ ushort Vs[2][64][36];                              // 72B rows
    __shared__ ushort p_lds[4][16][36] __attribute__((aligned(16)));

    const int tid  = threadIdx.x;
    const int wave = tid >> 6, lane = tid & 63;
    const int lq = lane & 15, lg = lane >> 4;
    const int qg = blockIdx.x >> 3, s = blockIdx.x & 7;   // split <-> XCD
    const int qtg = qg * 4 + wave;          // global q-tile id, 0..1023
    const int b   = qtg >> 8;
    const int q0  = (qtg & 255) << 4;

    const ushort* Qb = Q  + ((size_t)b * N + q0) * C;
    const ushort* Kb = K  + (size_t)b * N * C + (size_t)s * CHUNK * C;
    const ushort* Vb = Vt + (size_t)b * C * N + (size_t)s * CHUNK;

    const int krow = tid >> 3, kseg = tid & 7;
    const int vrow = tid >> 2, vseg = tid & 3;
    const ushort* kgp = Kb + (size_t)krow * C + kseg * 8;
    const ushort* vgp = Vb + (size_t)vrow * N + vseg * 8;

    const bf16x8 qf0 = *(const bf16x8*)(Qb + (size_t)lq * C + lg * 8);
    const bf16x8 qf1 = *(const bf16x8*)(Qb + (size_t)lq * C + 32 + lg * 8);

    f32x4 acc[4];
#pragma unroll
    for (int nt = 0; nt < 4; ++nt) acc[nt] = (f32x4){0.f, 0.f, 0.f, 0.f};
    float psum[4] = {0.f, 0.f, 0.f, 0.f};

    {   // prologue: stage tile 0
        bf16x8 kv = *(const bf16x8*)kgp;
        bf16x8 vv = *(const bf16x8*)vgp;
        *(bf16x8*)&Ks[0][krow][kseg * 8] = kv;
        *(bf16x8*)&Vs[0][vrow][vseg * 8] = vv;
    }
    __syncthreads();

    constexpr int NT = CHUNK / 32;   // 16 tiles
    for (int t = 0; t < NT; ++t) {
        const int cur = t & 1;
        bf16x8 knx, vnx;
        if (t + 1 < NT) {   // T14: issue next tile's loads early
            knx = *(const bf16x8*)(kgp + (size_t)(t + 1) * 32 * C);
            vnx = *(const bf16x8*)(vgp + (t + 1) * 32);
        }

        const bf16x8 k00 = *(const bf16x8*)&Ks[cur][lq][lg * 8];
        const bf16x8 k01 = *(const bf16x8*)&Ks[cur][lq][32 + lg * 8];
        const bf16x8 k10 = *(const bf16x8*)&Ks[cur][16 + lq][lg * 8];
        const bf16x8 k11 = *(const bf16x8*)&Ks[cur][16 + lq][32 + lg * 8];

        f32x4 s0 = (f32x4){0.f, 0.f, 0.f, 0.f};
        f32x4 s1 = (f32x4){0.f, 0.f, 0.f, 0.f};
        s0 = MFMA16(qf0, k00, s0);
        s0 = MFMA16(qf1, k01, s0);
        s1 = MFMA16(qf0, k10, s1);
        s1 = MFMA16(qf1, k11, s1);

        float p0v[4], p1v[4];
#pragma unroll
        for (int j = 0; j < 4; ++j) {
            p0v[j] = __expf(fminf(s0[j], 30.f));
            p1v[j] = __expf(fminf(s1[j], 30.f));
            psum[j] += p0v[j] + p1v[j];     // deferred denominator
        }
#pragma unroll
        for (int j = 0; j < 4; ++j) {
            const int row = lg * 4 + j;
            p_lds[wave][row][lq]      = f2bf(p0v[j]);
            p_lds[wave][row][lq + 16] = f2bf(p1v[j]);
        }
        const bf16x8 pa = *(const bf16x8*)&p_lds[wave][lq][lg * 8];
#pragma unroll
        for (int nt = 0; nt < 4; ++nt) {
            const bf16x8 vf = *(const bf16x8*)&Vs[cur][nt * 16 + lq][lg * 8];
            acc[nt] = MFMA16(pa, vf, acc[nt]);
        }

        if (t + 1 < NT) {
            *(bf16x8*)&Ks[cur ^ 1][krow][kseg * 8] = knx;
            *(bf16x8*)&Vs[cur ^ 1][vrow][vseg * 8] = vnx;
        }
        __syncthreads();
    }

#pragma unroll
    for (int off = 1; off < 16; off <<= 1) {
#pragma unroll
        for (int j = 0; j < 4; ++j) psum[j] += __shfl_xor(psum[j], off);
    }

    // split-combine via device-scope fp32 atomics (linear: no-max softmax)
    float* hb = HT + ((size_t)b * N + q0) * 64;
#pragma unroll
    for (int nt = 0; nt < 4; ++nt)
#pragma unroll
        for (int j = 0; j < 4; ++j)
            atomicAdd(&hb[(lg * 4 + j) * 64 + nt * 16 + lq], acc[nt][j]);
    if (lq == 0) {
#pragma unroll
        for (int j = 0; j < 4; ++j)
            atomicAdd(&l[(size_t)b * N + q0 + lg * 4 + j], psum[j]);
    }
}

// ---------------------------------------------------------------------------
// Kernel 3: projection + residual. Zero LDS, zero barriers.
// B-frag = direct global float4 loads of HT row n=lq, 1/l folded pre-convert.
// ---------------------------------------------------------------------------
__global__ __launch_bounds__(256) void proj_kernel(
    const float* __restrict__ x, const float* __restrict__ Wp,
    const float* __restrict__ HT, const float* __restrict__ l,
    float* __restrict__ out)
{
    const int tid = threadIdx.x;
    const int b   = blockIdx.x >> 7;
    const int n0  = (blockIdx.x & 127) << 5;
    const int lane = tid & 63, w = tid >> 6;
    const int lq = lane & 15, lg = lane >> 4;

    bf16x8 af[2];
#pragma unroll
    for (int kk = 0; kk < 2; ++kk) {
        const float* wp = Wp + (size_t)(w * 16 + lq) * C + kk * 32 + lg * 8;
        const float4 w0 = *(const float4*)wp;
        const float4 w1 = *(const float4*)(wp + 4);
        af[kk] = pack8(packbf2(w0.x, w0.y), packbf2(w0.z, w0.w),
                       packbf2(w1.x, w1.y), packbf2(w1.z, w1.w));
    }

#pragma unroll
    for (int th = 0; th < 2; ++th) {
        const int n = n0 + th * 16 + lq;
        const float li = 1.0f / l[(size_t)b * N + n];
        const float* hp = HT + ((size_t)b * N + n) * 64;
        f32x4 acc = {0.f, 0.f, 0.f, 0.f};
#pragma unroll
        for (int kk = 0; kk < 2; ++kk) {
            const float4 h0 = *(const float4*)(hp + kk * 32 + lg * 8);
            const float4 h1 = *(const float4*)(hp + kk * 32 + lg * 8 + 4);
            const bf16x8 bf = pack8(
                packbf2(h0.x * li, h0.y * li), packbf2(h0.z * li, h0.w * li),
                packbf2(h1.x * li, h1.y * li), packbf2(h1.z * li, h1.w * li));
            acc = MFMA16(af[kk], bf, acc);
        }
#pragma unroll
        for (int j = 0; j < 4; ++j) {
            const int o = w * 16 + 4 * lg + j;
            const size_t idx = (size_t)(b * C + o) * N + n;
            out[idx] = x[idx] + acc[j];
        }
    }
}

// ---------------------------------------------------------------------------
extern "C" void kernel_launch(void* const* d_in, const int* in_sizes, int n_in,
                              void* d_out, int out_size, void* d_ws, size_t ws_size,
                              hipStream_t stream)
{
    const float* x  = (const float*)d_in[0];
    const float* Wq = (const float*)d_in[1];
    const float* Wk = (const float*)d_in[2];
    const float* Wv = (const float*)d_in[3];
    const float* Wp = (const float*)d_in[4];
    float* out = (float*)d_out;

    // workspace: Q,K,Vt bf16 2MB each + HT fp32 4MB + l fp32 64KB = 10.1MB
    ushort* Q  = (ushort*)d_ws;
    ushort* K  = Q  + (size_t)B * N * C;
    ushort* Vt = K  + (size_t)B * N * C;
    float*  HT = (float*)(Vt + (size_t)B * N * C);
    float*  l  = HT + (size_t)B * N * C;

    qkv_kernel<<<B * 256, 256, 0, stream>>>(x, Wq, Wk, Wv, Q, K, Vt, HT, l);
    attn_kernel<<<256 * KVSPLIT, 256, 0, stream>>>(Q, K, Vt, HT, l);
    proj_kernel<<<B * 128, 256, 0, stream>>>(x, Wp, HT, l, out);
}